// Round 13
// baseline (345.576 us; speedup 1.0000x reference)
//
#include <hip/hip_runtime.h>
#include <hip/hip_fp16.h>
#include <math.h>

#define N_NODES 100000
#define N_EDGES 1600000
#define E_TOT   (N_EDGES + N_NODES)

// bucketed CSR build
#define NB     512          // buckets
#define NPB    196          // dst-nodes per bucket (512*196 = 100352 >= N)
#define BCAP   4096         // capacity per bucket (mean 3332, +13 sigma)
#define BIN_CH 4096         // edges per bin_k workgroup
#define NBIN_WG ((E_TOT + BIN_CH - 1) / BIN_CH)

#define PAN1H ((size_t)N_NODES * 64)   // halves per h1 panel (64 cols)

typedef __attribute__((ext_vector_type(8))) short short8v;      // 8 bf16
typedef __attribute__((ext_vector_type(8))) _Float16 half8v;    // 8 fp16
typedef __attribute__((ext_vector_type(4))) float float4v;

__device__ __forceinline__ float wexp(float v) {
    v = v > 0.f ? v : 0.2f * v;
    return __expf(v);
}

__device__ __forceinline__ unsigned short f2bf(float f) {
    unsigned u = __float_as_uint(f);
    return (unsigned short)((u + 0x7FFFu + ((u >> 16) & 1u)) >> 16);
}

// ---------------------------------------------------------------------------
// xprep: x fp32 -> bf16 (row-major). 4 elems/thread.
// ---------------------------------------------------------------------------
__global__ __launch_bounds__(256) void xprep_k(
    const float* __restrict__ x, unsigned short* __restrict__ xb)
{
    int gid = blockIdx.x * 256 + threadIdx.x;     // covers N*128/4 exactly
    float4 v = ((const float4*)x)[gid];
    ushort4 o;
    o.x = f2bf(v.x); o.y = f2bf(v.y); o.z = f2bf(v.z); o.w = f2bf(v.w);
    ((ushort4*)xb)[gid] = o;
}

// ---------------------------------------------------------------------------
// w1prep: W1 -> bf16 fragment order [kstep][colfrag][lane][8].
// ---------------------------------------------------------------------------
__global__ __launch_bounds__(256) void w1prep_k(
    const float* __restrict__ W1, unsigned short* __restrict__ W1b)
{
    for (int idx = threadIdx.x; idx < 16384; idx += 256) {
        int i    = idx & 7;
        int lane = (idx >> 3) & 63;
        int f    = (idx >> 9) & 7;
        int ks   = idx >> 12;
        int k   = ks * 32 + (lane >> 4) * 8 + i;
        int col = f * 16 + (lane & 15);
        W1b[idx] = f2bf(W1[k * 128 + col]);
    }
}

// ---------------------------------------------------------------------------
// w2prep: W2 -> fp16 fragment order [ks][f][lane][8], 3 col-frags (48 cols,
// cols 40..47 zero). 6144 halves.
// ---------------------------------------------------------------------------
__global__ __launch_bounds__(256) void w2prep_k(
    const float* __restrict__ W2, __half* __restrict__ W2h)
{
    for (int idx = threadIdx.x; idx < 6144; idx += 256) {
        int i    = idx & 7;
        int lane = (idx >> 3) & 63;
        int rest = idx >> 9;          // 0..11
        int f = rest % 3, ks = rest / 3;
        int k   = ks * 32 + (lane >> 4) * 8 + i;
        int col = f * 16 + (lane & 15);
        W2h[idx] = __float2half_rn(col < 40 ? W2[k * 40 + col] : 0.f);
    }
}

// ---------------------------------------------------------------------------
// GEMM1 (MFMA bf16): h1 = x @ W1, stored as 2 PANELS h1p[p][node][64] fp16
// (panel p = cols p*64..p*64+63; 128B rows). Fused alpha reductions.
// C/D: col=lane&15, row=(lane>>4)*4+reg.
// ---------------------------------------------------------------------------
__global__ __launch_bounds__(256) void gemm1_k(
    const unsigned short* __restrict__ xb, const unsigned short* __restrict__ W1b,
    const float* __restrict__ as1, const float* __restrict__ ad1,
    __half* __restrict__ h1p, float* __restrict__ asrc, float* __restrict__ adst)
{
    const int t = threadIdx.x;
    const int w = t >> 6, L = t & 63;
    const int lr = L & 15;            // A-row / C-col within frag
    const int lg = L >> 4;            // k-group / C row-group
    const int nbase = blockIdx.x * 64 + w * 16;

    float4v acc[8];
#pragma unroll
    for (int f = 0; f < 8; ++f) acc[f] = (float4v)0.f;

    int arow = nbase + lr; if (arow >= N_NODES) arow = N_NODES - 1;
    const unsigned short* xrow = xb + (size_t)arow * 128 + lg * 8;

#pragma unroll
    for (int ks = 0; ks < 4; ++ks) {
        short8v a = *(const short8v*)(xrow + ks * 32);
        const unsigned short* wb = W1b + ((size_t)ks * 8 * 64 + L) * 8;
#pragma unroll
        for (int f = 0; f < 8; ++f) {
            short8v b = *(const short8v*)(wb + (size_t)f * 512);
            acc[f] = __builtin_amdgcn_mfma_f32_16x16x32_bf16(a, b, acc[f], 0, 0, 0);
        }
    }

    float as_v[8], ad_v[8];
#pragma unroll
    for (int f = 0; f < 8; ++f) {
        as_v[f] = as1[f * 16 + lr];
        ad_v[f] = ad1[f * 16 + lr];
    }

#pragma unroll
    for (int r = 0; r < 4; ++r) {
        int node = nbase + lg * 4 + r;
        bool ok = node < N_NODES;
        if (ok) {
#pragma unroll
            for (int f = 0; f < 8; ++f)
                h1p[(size_t)(f >> 2) * PAN1H + (size_t)node * 64 + (f & 3) * 16 + lr]
                    = __float2half_rn(acc[f][r]);
        }
        float ps0 = 0.f, pd0 = 0.f, ps1 = 0.f, pd1 = 0.f;
#pragma unroll
        for (int f = 0; f < 4; ++f) { ps0 += acc[f][r] * as_v[f]; pd0 += acc[f][r] * ad_v[f]; }
#pragma unroll
        for (int f = 4; f < 8; ++f) { ps1 += acc[f][r] * as_v[f]; pd1 += acc[f][r] * ad_v[f]; }
#pragma unroll
        for (int off = 1; off < 16; off <<= 1) {
            ps0 += __shfl_xor(ps0, off); pd0 += __shfl_xor(pd0, off);
            ps1 += __shfl_xor(ps1, off); pd1 += __shfl_xor(pd1, off);
        }
        if (lr == 0 && ok) {
            asrc[node * 2 + 0] = ps0; asrc[node * 2 + 1] = ps1;
            adst[node * 2 + 0] = pd0; adst[node * 2 + 1] = pd1;
        }
    }
}

// ---------------------------------------------------------------------------
// CSR build, phase 1: bin edges by dst bucket. Edges read ONCE into regs.
// ---------------------------------------------------------------------------
__global__ __launch_bounds__(256) void bin_k(
    const int* __restrict__ ei, int* __restrict__ bcur, unsigned* __restrict__ bdata)
{
    __shared__ int hist[NB];
    __shared__ int base[NB];
    const int t = threadIdx.x;
    const int e0 = blockIdx.x * BIN_CH;

    int rs[16], rd[16];
#pragma unroll
    for (int p = 0; p < 16; ++p) {
        int e = e0 + p * 256 + t;
        if (e < E_TOT) {
            if (e < N_EDGES) { rs[p] = ei[e]; rd[p] = ei[N_EDGES + e]; }
            else             { rs[p] = rd[p] = e - N_EDGES; }
        } else rd[p] = -1;
    }

    for (int b = t; b < NB; b += 256) hist[b] = 0;
    __syncthreads();

#pragma unroll
    for (int p = 0; p < 16; ++p)
        if (rd[p] >= 0) atomicAdd(&hist[rd[p] / NPB], 1);
    __syncthreads();

    for (int b = t; b < NB; b += 256) {
        int c = hist[b];
        base[b] = c ? atomicAdd(&bcur[b], c) : 0;
        hist[b] = 0;      // reuse as local cursor
    }
    __syncthreads();

#pragma unroll
    for (int p = 0; p < 16; ++p) {
        if (rd[p] < 0) continue;
        int b  = rd[p] / NPB;
        int dl = rd[p] - b * NPB;
        int pos = base[b] + atomicAdd(&hist[b], 1);
        if (pos < BCAP)
            bdata[(size_t)b * BCAP + pos] = (unsigned)rs[p] | ((unsigned)dl << 17);
    }
}

// ---------------------------------------------------------------------------
// CSR build, phase 2a: exclusive scan of bucket counts (1 wg x 512 threads).
// ---------------------------------------------------------------------------
__global__ __launch_bounds__(512) void scanb_k(
    const int* __restrict__ bcur, int* __restrict__ bbase)
{
    __shared__ int a[NB], b_[NB];
    int t = threadIdx.x;
    int v = bcur[t];
    a[t] = v;
    __syncthreads();
    int* src = a; int* dst = b_;
    for (int off = 1; off < NB; off <<= 1) {
        dst[t] = (t >= off) ? src[t - off] + src[t] : src[t];
        __syncthreads();
        int* tmp = src; src = dst; dst = tmp;
    }
    bbase[t] = src[t] - v;   // exclusive
}

// ---------------------------------------------------------------------------
// CSR build, phase 2b: wg per bucket -> row_start + csr_src (contiguous).
// ---------------------------------------------------------------------------
__global__ __launch_bounds__(256) void build_k(
    const unsigned* __restrict__ bdata, const int* __restrict__ bcur,
    const int* __restrict__ bbase, int* __restrict__ row_start,
    int* __restrict__ csr_src)
{
    __shared__ unsigned rec[BCAP];     // 16 KB
    __shared__ int hist[256];
    __shared__ int excl[NPB];
    __shared__ int lcur[NPB];
    const int t = threadIdx.x;
    const int b = blockIdx.x;
    const int cnt = min(bcur[b], BCAP);
    const int bb = bbase[b];

    hist[t] = 0;
    if (t < NPB) lcur[t] = 0;
    __syncthreads();

    for (int i = t; i < cnt; i += 256) {
        unsigned r = bdata[(size_t)b * BCAP + i];
        rec[i] = r;
        atomicAdd(&hist[r >> 17], 1);
    }
    __syncthreads();

    int v = hist[t];
    __syncthreads();
    for (int off = 1; off < 256; off <<= 1) {
        int y = (t >= off) ? hist[t - off] : 0;
        __syncthreads();
        hist[t] += y;
        __syncthreads();
    }
    if (t < NPB) excl[t] = hist[t] - v;
    __syncthreads();

    int node = b * NPB + t;
    if (t < NPB && node <= N_NODES) row_start[node] = bb + excl[t];

    for (int i = t; i < cnt; i += 256) {
        unsigned r = rec[i];
        int dl = r >> 17;
        int s  = r & 0x1FFFF;
        int slot = atomicAdd(&lcur[dl], 1);
        csr_src[bb + excl[dl] + slot] = s;
    }
}

// ---------------------------------------------------------------------------
// Fused layer-1 aggregation, 2-way column slice: slice = blockIdx&1 -> one
// 64-col panel (12.8 MB; even/odd XCDs each stream only their panel).
// Wave = 2 edge-slots x 32 cols; per edge gather = one full 128B line.
// Head = slice. 4-deep unroll (8 edges in flight). Bias + ELU epilogue.
// ---------------------------------------------------------------------------
__global__ __launch_bounds__(256) void fagg1_k(
    const int* __restrict__ csr_src, const int* __restrict__ row_start,
    const float* __restrict__ asrc, const float* __restrict__ adst,
    const __half* __restrict__ h1p, const float* __restrict__ b1,
    __half* __restrict__ out1h)
{
    const int slice = blockIdx.x & 1;
    const int node = (blockIdx.x >> 1) * 4 + (threadIdx.x >> 6);
    const int L = threadIdx.x & 63;
    const int eslot = L >> 5;          // 0..1
    const int c32 = L & 31;            // half2 index within panel row
    const int b = row_start[node], e = row_start[node + 1];
    const float* as_h = asrc + slice;  // head = slice; index with s*2
    const float ad = adst[node * 2 + slice];
    const __half2* P = (const __half2*)(h1p + (size_t)slice * PAN1H);

    float2 a0 = make_float2(0.f, 0.f), a1 = a0, a2 = a0, a3 = a0;
    float d0 = 0.f, d1 = 0.f, d2 = 0.f, d3 = 0.f;

    int j = b;
    for (; j + 7 < e; j += 8) {
        int s0 = csr_src[j + 0 + eslot];
        int s1 = csr_src[j + 2 + eslot];
        int s2 = csr_src[j + 4 + eslot];
        int s3 = csr_src[j + 6 + eslot];
        float w0 = wexp(as_h[s0 * 2] + ad);
        float w1 = wexp(as_h[s1 * 2] + ad);
        float w2 = wexp(as_h[s2 * 2] + ad);
        float w3 = wexp(as_h[s3 * 2] + ad);
        float2 x0 = __half22float2(P[(size_t)s0 * 32 + c32]);
        float2 x1 = __half22float2(P[(size_t)s1 * 32 + c32]);
        float2 x2 = __half22float2(P[(size_t)s2 * 32 + c32]);
        float2 x3 = __half22float2(P[(size_t)s3 * 32 + c32]);
        a0.x += w0 * x0.x; a0.y += w0 * x0.y; d0 += w0;
        a1.x += w1 * x1.x; a1.y += w1 * x1.y; d1 += w1;
        a2.x += w2 * x2.x; a2.y += w2 * x2.y; d2 += w2;
        a3.x += w3 * x3.x; a3.y += w3 * x3.y; d3 += w3;
    }
    for (; j < e; ++j) {                 // tail: eslot 1 contributes 0
        int s = csr_src[j];
        float w = (eslot == 0) ? wexp(as_h[s * 2] + ad) : 0.f;
        float2 xv = __half22float2(P[(size_t)s * 32 + c32]);
        a0.x += w * xv.x; a0.y += w * xv.y; d0 += w;
    }

    float den = (d0 + d1) + (d2 + d3);
    float sx  = (a0.x + a1.x) + (a2.x + a3.x);
    float sy  = (a0.y + a1.y) + (a2.y + a3.y);
    sx  += __shfl_xor(sx, 32);
    sy  += __shfl_xor(sy, 32);
    den += __shfl_xor(den, 32);

    float inv = 1.f / (den + 1e-16f);
    int col2 = slice * 32 + c32;         // half2 index within 128-col row
    float2 bb = ((const float2*)b1)[col2];
    float vx = sx * inv + bb.x;
    float vy = sy * inv + bb.y;
    vx = vx > 0.f ? vx : expm1f(vx);
    vy = vy > 0.f ? vy : expm1f(vy);
    if (eslot == 0)
        ((__half2*)(out1h + (size_t)node * 128))[col2] = __floats2half2_rn(vx, vy);
}

// ---------------------------------------------------------------------------
// GEMM2 (MFMA fp16): h2[N,64pad fp16] = out1[N,128] @ W2[128,40].
// Wave = 16 nodes x 48 cols: 4 K-steps x 3 col-frags. Fused alpha2.
// ---------------------------------------------------------------------------
__global__ __launch_bounds__(256) void gemm2_k(
    const __half* __restrict__ out1h, const __half* __restrict__ W2h,
    const float* __restrict__ as2, const float* __restrict__ ad2,
    __half* __restrict__ h2h, float* __restrict__ asrc, float* __restrict__ adst)
{
    const int t = threadIdx.x;
    const int w = t >> 6, L = t & 63;
    const int lr = L & 15, lg = L >> 4;
    const int nbase = blockIdx.x * 64 + w * 16;

    float4v acc[3];
#pragma unroll
    for (int f = 0; f < 3; ++f) acc[f] = (float4v)0.f;

    int arow = nbase + lr; if (arow >= N_NODES) arow = N_NODES - 1;
    const __half* xrow = out1h + (size_t)arow * 128 + lg * 8;

#pragma unroll
    for (int ks = 0; ks < 4; ++ks) {
        half8v a = *(const half8v*)(xrow + ks * 32);
        const __half* wb = W2h + (size_t)ks * 1536 + (size_t)L * 8;
#pragma unroll
        for (int f = 0; f < 3; ++f) {
            half8v bfr = *(const half8v*)(wb + (size_t)f * 512);
            acc[f] = __builtin_amdgcn_mfma_f32_16x16x32_f16(a, bfr, acc[f], 0, 0, 0);
        }
    }

    float as_v[3], ad_v[3];
#pragma unroll
    for (int f = 0; f < 3; ++f) {
        int c = f * 16 + lr;
        as_v[f] = (c < 40) ? as2[c] : 0.f;
        ad_v[f] = (c < 40) ? ad2[c] : 0.f;
    }

#pragma unroll
    for (int r = 0; r < 4; ++r) {
        int node = nbase + lg * 4 + r;
        bool ok = node < N_NODES;
        if (ok) {
#pragma unroll
            for (int f = 0; f < 3; ++f)
                h2h[(size_t)node * 64 + f * 16 + lr] = __float2half_rn(acc[f][r]);
        }
        float ps = acc[0][r] * as_v[0] + acc[1][r] * as_v[1] + acc[2][r] * as_v[2];
        float pd = acc[0][r] * ad_v[0] + acc[1][r] * ad_v[1] + acc[2][r] * ad_v[2];
#pragma unroll
        for (int off = 1; off < 16; off <<= 1) {
            ps += __shfl_xor(ps, off);
            pd += __shfl_xor(pd, off);
        }
        if (lr == 0 && ok) {
            asrc[node] = ps;
            adst[node] = pd;
        }
    }
}

// ---------------------------------------------------------------------------
// Fused layer-2 aggregation + bias + log_softmax (R10 4-wide form).
// ---------------------------------------------------------------------------
__global__ __launch_bounds__(256) void fagg2_k(
    const int* __restrict__ csr_src, const int* __restrict__ row_start,
    const float* __restrict__ asrc, const float* __restrict__ adst,
    const __half* __restrict__ h2h, const float* __restrict__ b2,
    float* __restrict__ out)
{
    int node = blockIdx.x * 4 + (threadIdx.x >> 6);
    int L = threadIdx.x & 63;
    bool act = L < 40;
    int col = act ? L : 0;
    int b = row_start[node], e = row_start[node + 1];
    float ad = adst[node];

    float a0 = 0.f, a1 = 0.f, a2 = 0.f, a3 = 0.f;
    float d0 = 0.f, d1 = 0.f, d2 = 0.f, d3 = 0.f;

    int j = b;
    for (; j + 3 < e; j += 4) {
        int s0 = csr_src[j], s1 = csr_src[j + 1], s2 = csr_src[j + 2], s3 = csr_src[j + 3];
        float w0 = wexp(asrc[s0] + ad);
        float w1 = wexp(asrc[s1] + ad);
        float w2 = wexp(asrc[s2] + ad);
        float w3 = wexp(asrc[s3] + ad);
        float x0 = __half2float(h2h[(size_t)s0 * 64 + col]);
        float x1 = __half2float(h2h[(size_t)s1 * 64 + col]);
        float x2 = __half2float(h2h[(size_t)s2 * 64 + col]);
        float x3 = __half2float(h2h[(size_t)s3 * 64 + col]);
        a0 += w0 * x0; d0 += w0;
        a1 += w1 * x1; d1 += w1;
        a2 += w2 * x2; d2 += w2;
        a3 += w3 * x3; d3 += w3;
    }
    for (; j < e; ++j) {
        int s = csr_src[j];
        float w = wexp(asrc[s] + ad);
        float xv = __half2float(h2h[(size_t)s * 64 + col]);
        a0 += w * xv; d0 += w;
    }

    float den = (d0 + d1) + (d2 + d3);
    float acc = (a0 + a1) + (a2 + a3);
    float v = act ? acc / (den + 1e-16f) + b2[L] : -1e30f;
    float mx = v;
#pragma unroll
    for (int off = 32; off; off >>= 1) mx = fmaxf(mx, __shfl_xor(mx, off));
    float ex = act ? __expf(v - mx) : 0.f;
#pragma unroll
    for (int off = 32; off; off >>= 1) ex += __shfl_xor(ex, off);
    if (act) out[(size_t)node * 40 + L] = v - mx - logf(ex);
}

// ---------------------------------------------------------------------------
extern "C" void kernel_launch(void* const* d_in, const int* in_sizes, int n_in,
                              void* d_out, int out_size, void* d_ws, size_t ws_size,
                              hipStream_t stream)
{
    const float* x   = (const float*)d_in[0];
    const int*   ei  = (const int*)d_in[1];
    const float* W1  = (const float*)d_in[2];
    const float* as1 = (const float*)d_in[3];
    const float* ad1 = (const float*)d_in[4];
    const float* b1  = (const float*)d_in[5];
    const float* W2  = (const float*)d_in[6];
    const float* as2 = (const float*)d_in[7];
    const float* ad2 = (const float*)d_in[8];
    const float* b2  = (const float*)d_in[9];
    float* out = (float*)d_out;

    float* ws = (float*)d_ws;
    // workspace layout (4B units); total ~27.4M = 109.6 MB
    __half* h1p   = (__half*)ws;                  // 2 panels x N*64 halves = N*128 halves; reused as h2h (N*64)
    __half* out1h = (__half*)(ws + 6400000);      // N*128 halves
    float* asrc1 = ws + 19200000;                 // 2N
    float* adst1 = ws + 19400000;                 // 2N
    float* asrc2 = ws + 19600000;                 // N
    float* adst2 = ws + 19700000;                 // N
    int* bcur      = (int*)(ws + 20110000);       // NB
    int* bbase     = (int*)(ws + 20111000);       // NB
    int* row_start = (int*)(ws + 20112000);       // N+1
    int* csr_src   = (int*)(ws + 20220000);       // E_TOT
    unsigned* bdata = (unsigned*)(ws + 22000000); // NB*BCAP = 2.1M
    unsigned short* xb  = (unsigned short*)(ws + 24100000);  // N*128 bf16
    unsigned short* W1b = (unsigned short*)(ws + 27300000);  // 16384 bf16
    __half* W2h = (__half*)(ws + 27310000);       // 6144 fp16

    // zero bucket cursors only (2 KB)
    hipMemsetAsync(bcur, 0, NB * sizeof(int), stream);

    // prep: x -> bf16, W1/W2 -> fragment order
    xprep_k<<<12500, 256, 0, stream>>>(x, xb);
    w1prep_k<<<1, 256, 0, stream>>>(W1, W1b);
    w2prep_k<<<1, 256, 0, stream>>>(W2, W2h);

    // CSR build: bin -> scan -> build
    bin_k<<<NBIN_WG, 256, 0, stream>>>(ei, bcur, bdata);
    scanb_k<<<1, 512, 0, stream>>>(bcur, bbase);
    build_k<<<NB, 256, 0, stream>>>(bdata, bcur, bbase, row_start, csr_src);

    // layer 1
    gemm1_k<<<1563, 256, 0, stream>>>(xb, W1b, as1, ad1, h1p, asrc1, adst1);
    fagg1_k<<<50000, 256, 0, stream>>>(csr_src, row_start, asrc1, adst1, h1p, b1, out1h);

    // layer 2 (h2h reuses h1p region, stride 64 halves = one 128B line)
    __half* h2h = (__half*)h1p;
    gemm2_k<<<1563, 256, 0, stream>>>(out1h, W2h, as2, ad2, h2h, asrc2, adst2);
    fagg2_k<<<25000, 256, 0, stream>>>(csr_src, row_start, asrc2, adst2, h2h, b2, out);
}

// Round 14
// 269.225 us; speedup vs baseline: 1.2836x; 1.2836x over previous
//
#include <hip/hip_runtime.h>
#include <hip/hip_fp16.h>
#include <math.h>

#define N_NODES 100000
#define N_EDGES 1600000
#define E_TOT   (N_EDGES + N_NODES)

// bucketed CSR build
#define NB     512          // buckets
#define NPB    196          // dst-nodes per bucket (512*196 = 100352 >= N)
#define BCAP   4096         // capacity per bucket (mean 3332, +13 sigma)
#define BIN_CH 4096         // edges per bin_k workgroup
#define NBIN_WG ((E_TOT + BIN_CH - 1) / BIN_CH)

typedef __attribute__((ext_vector_type(8))) short short8v;      // 8 bf16
typedef __attribute__((ext_vector_type(8))) _Float16 half8v;    // 8 fp16
typedef __attribute__((ext_vector_type(4))) float float4v;

__device__ __forceinline__ float wexp(float v) {
    v = v > 0.f ? v : 0.2f * v;
    return __expf(v);
}

__device__ __forceinline__ unsigned short f2bf(float f) {
    unsigned u = __float_as_uint(f);
    return (unsigned short)((u + 0x7FFFu + ((u >> 16) & 1u)) >> 16);
}

// ---------------------------------------------------------------------------
// xprep: x fp32 -> bf16 (row-major). 4 elems/thread.
// ---------------------------------------------------------------------------
__global__ __launch_bounds__(256) void xprep_k(
    const float* __restrict__ x, unsigned short* __restrict__ xb)
{
    int gid = blockIdx.x * 256 + threadIdx.x;     // covers N*128/4 exactly
    float4 v = ((const float4*)x)[gid];
    ushort4 o;
    o.x = f2bf(v.x); o.y = f2bf(v.y); o.z = f2bf(v.z); o.w = f2bf(v.w);
    ((ushort4*)xb)[gid] = o;
}

// ---------------------------------------------------------------------------
// w1prep: W1 -> bf16 fragment order [kstep][colfrag][lane][8].
// ---------------------------------------------------------------------------
__global__ __launch_bounds__(256) void w1prep_k(
    const float* __restrict__ W1, unsigned short* __restrict__ W1b)
{
    for (int idx = threadIdx.x; idx < 16384; idx += 256) {
        int i    = idx & 7;
        int lane = (idx >> 3) & 63;
        int f    = (idx >> 9) & 7;
        int ks   = idx >> 12;
        int k   = ks * 32 + (lane >> 4) * 8 + i;
        int col = f * 16 + (lane & 15);
        W1b[idx] = f2bf(W1[k * 128 + col]);
    }
}

// ---------------------------------------------------------------------------
// w2prep: W2 -> fp16 fragment order [ks][f][lane][8], 3 col-frags (48 cols,
// cols 40..47 zero). 6144 halves.
// ---------------------------------------------------------------------------
__global__ __launch_bounds__(256) void w2prep_k(
    const float* __restrict__ W2, __half* __restrict__ W2h)
{
    for (int idx = threadIdx.x; idx < 6144; idx += 256) {
        int i    = idx & 7;
        int lane = (idx >> 3) & 63;
        int rest = idx >> 9;          // 0..11
        int f = rest % 3, ks = rest / 3;
        int k   = ks * 32 + (lane >> 4) * 8 + i;
        int col = f * 16 + (lane & 15);
        W2h[idx] = __float2half_rn(col < 40 ? W2[k * 40 + col] : 0.f);
    }
}

// ---------------------------------------------------------------------------
// GEMM1 (MFMA bf16): h1[N,128] = x @ W1, fp16 out; fused alpha reductions.
// Wave = 16 nodes x 128 cols: 4 K-steps x 8 col-frags of 16x16x32.
// C/D: col=lane&15, row=(lane>>4)*4+reg (m89-verified mapping).
// ---------------------------------------------------------------------------
__global__ __launch_bounds__(256) void gemm1_k(
    const unsigned short* __restrict__ xb, const unsigned short* __restrict__ W1b,
    const float* __restrict__ as1, const float* __restrict__ ad1,
    __half* __restrict__ h1h, float* __restrict__ asrc, float* __restrict__ adst)
{
    const int t = threadIdx.x;
    const int w = t >> 6, L = t & 63;
    const int lr = L & 15;            // A-row / C-col within frag
    const int lg = L >> 4;            // k-group / C row-group
    const int nbase = blockIdx.x * 64 + w * 16;

    float4v acc[8];
#pragma unroll
    for (int f = 0; f < 8; ++f) acc[f] = (float4v)0.f;

    int arow = nbase + lr; if (arow >= N_NODES) arow = N_NODES - 1;
    const unsigned short* xrow = xb + (size_t)arow * 128 + lg * 8;

#pragma unroll
    for (int ks = 0; ks < 4; ++ks) {
        short8v a = *(const short8v*)(xrow + ks * 32);
        const unsigned short* wb = W1b + ((size_t)ks * 8 * 64 + L) * 8;
#pragma unroll
        for (int f = 0; f < 8; ++f) {
            short8v b = *(const short8v*)(wb + (size_t)f * 512);
            acc[f] = __builtin_amdgcn_mfma_f32_16x16x32_bf16(a, b, acc[f], 0, 0, 0);
        }
    }

    float as_v[8], ad_v[8];
#pragma unroll
    for (int f = 0; f < 8; ++f) {
        as_v[f] = as1[f * 16 + lr];
        ad_v[f] = ad1[f * 16 + lr];
    }

#pragma unroll
    for (int r = 0; r < 4; ++r) {
        int node = nbase + lg * 4 + r;
        bool ok = node < N_NODES;
        if (ok) {
#pragma unroll
            for (int f = 0; f < 8; ++f)
                h1h[(size_t)node * 128 + f * 16 + lr] = __float2half_rn(acc[f][r]);
        }
        float ps0 = 0.f, pd0 = 0.f, ps1 = 0.f, pd1 = 0.f;
#pragma unroll
        for (int f = 0; f < 4; ++f) { ps0 += acc[f][r] * as_v[f]; pd0 += acc[f][r] * ad_v[f]; }
#pragma unroll
        for (int f = 4; f < 8; ++f) { ps1 += acc[f][r] * as_v[f]; pd1 += acc[f][r] * ad_v[f]; }
#pragma unroll
        for (int off = 1; off < 16; off <<= 1) {
            ps0 += __shfl_xor(ps0, off); pd0 += __shfl_xor(pd0, off);
            ps1 += __shfl_xor(ps1, off); pd1 += __shfl_xor(pd1, off);
        }
        if (lr == 0 && ok) {
            asrc[node * 2 + 0] = ps0; asrc[node * 2 + 1] = ps1;
            adst[node * 2 + 0] = pd0; adst[node * 2 + 1] = pd1;
        }
    }
}

// ---------------------------------------------------------------------------
// CSR build, phase 1: bin edges by dst bucket. Edges read ONCE into regs.
// ---------------------------------------------------------------------------
__global__ __launch_bounds__(256) void bin_k(
    const int* __restrict__ ei, int* __restrict__ bcur, unsigned* __restrict__ bdata)
{
    __shared__ int hist[NB];
    __shared__ int base[NB];
    const int t = threadIdx.x;
    const int e0 = blockIdx.x * BIN_CH;

    int rs[16], rd[16];
#pragma unroll
    for (int p = 0; p < 16; ++p) {
        int e = e0 + p * 256 + t;
        if (e < E_TOT) {
            if (e < N_EDGES) { rs[p] = ei[e]; rd[p] = ei[N_EDGES + e]; }
            else             { rs[p] = rd[p] = e - N_EDGES; }
        } else rd[p] = -1;
    }

    for (int b = t; b < NB; b += 256) hist[b] = 0;
    __syncthreads();

#pragma unroll
    for (int p = 0; p < 16; ++p)
        if (rd[p] >= 0) atomicAdd(&hist[rd[p] / NPB], 1);
    __syncthreads();

    for (int b = t; b < NB; b += 256) {
        int c = hist[b];
        base[b] = c ? atomicAdd(&bcur[b], c) : 0;
        hist[b] = 0;      // reuse as local cursor
    }
    __syncthreads();

#pragma unroll
    for (int p = 0; p < 16; ++p) {
        if (rd[p] < 0) continue;
        int b  = rd[p] / NPB;
        int dl = rd[p] - b * NPB;
        int pos = base[b] + atomicAdd(&hist[b], 1);
        if (pos < BCAP)
            bdata[(size_t)b * BCAP + pos] = (unsigned)rs[p] | ((unsigned)dl << 17);
    }
}

// ---------------------------------------------------------------------------
// CSR build, phase 2a: exclusive scan of bucket counts (1 wg x 512 threads).
// ---------------------------------------------------------------------------
__global__ __launch_bounds__(512) void scanb_k(
    const int* __restrict__ bcur, int* __restrict__ bbase)
{
    __shared__ int a[NB], b_[NB];
    int t = threadIdx.x;
    int v = bcur[t];
    a[t] = v;
    __syncthreads();
    int* src = a; int* dst = b_;
    for (int off = 1; off < NB; off <<= 1) {
        dst[t] = (t >= off) ? src[t - off] + src[t] : src[t];
        __syncthreads();
        int* tmp = src; src = dst; dst = tmp;
    }
    bbase[t] = src[t] - v;   // exclusive
}

// ---------------------------------------------------------------------------
// CSR build, phase 2b: wg per bucket -> row_start + csr_src (contiguous).
// ---------------------------------------------------------------------------
__global__ __launch_bounds__(256) void build_k(
    const unsigned* __restrict__ bdata, const int* __restrict__ bcur,
    const int* __restrict__ bbase, int* __restrict__ row_start,
    int* __restrict__ csr_src)
{
    __shared__ unsigned rec[BCAP];     // 16 KB
    __shared__ int hist[256];
    __shared__ int excl[NPB];
    __shared__ int lcur[NPB];
    const int t = threadIdx.x;
    const int b = blockIdx.x;
    const int cnt = min(bcur[b], BCAP);
    const int bb = bbase[b];

    hist[t] = 0;
    if (t < NPB) lcur[t] = 0;
    __syncthreads();

    for (int i = t; i < cnt; i += 256) {
        unsigned r = bdata[(size_t)b * BCAP + i];
        rec[i] = r;
        atomicAdd(&hist[r >> 17], 1);
    }
    __syncthreads();

    int v = hist[t];
    __syncthreads();
    for (int off = 1; off < 256; off <<= 1) {
        int y = (t >= off) ? hist[t - off] : 0;
        __syncthreads();
        hist[t] += y;
        __syncthreads();
    }
    if (t < NPB) excl[t] = hist[t] - v;
    __syncthreads();

    int node = b * NPB + t;
    if (t < NPB && node <= N_NODES) row_start[node] = bb + excl[t];

    for (int i = t; i < cnt; i += 256) {
        unsigned r = rec[i];
        int dl = r >> 17;
        int s  = r & 0x1FFFF;
        int slot = atomicAdd(&lcur[dl], 1);
        csr_src[bb + excl[dl] + slot] = s;
    }
}

// ---------------------------------------------------------------------------
// Fused layer-1 aggregation (R10/R7 proven form: 4-wide, inline exp).
// ---------------------------------------------------------------------------
__global__ __launch_bounds__(256) void fagg1_k(
    const int* __restrict__ csr_src, const int* __restrict__ row_start,
    const float* __restrict__ asrc, const float* __restrict__ adst,
    const __half* __restrict__ h1h, const float* __restrict__ b1,
    __half* __restrict__ out1h)
{
    int node = blockIdx.x * 4 + (threadIdx.x >> 6);
    int L = threadIdx.x & 63;
    int h = L >> 5;
    int b = row_start[node], e = row_start[node + 1];
    const float* as_h = asrc + h;
    float ad = adst[node * 2 + h];
    const __half2* H = (const __half2*)h1h;

    float2 a0 = make_float2(0.f, 0.f), a1 = a0, a2 = a0, a3 = a0;
    float d0 = 0.f, d1 = 0.f, d2 = 0.f, d3 = 0.f;

    int j = b;
    for (; j + 3 < e; j += 4) {
        int s0 = csr_src[j], s1 = csr_src[j + 1], s2 = csr_src[j + 2], s3 = csr_src[j + 3];
        float w0 = wexp(as_h[s0 * 2] + ad);
        float w1 = wexp(as_h[s1 * 2] + ad);
        float w2 = wexp(as_h[s2 * 2] + ad);
        float w3 = wexp(as_h[s3 * 2] + ad);
        float2 x0 = __half22float2(H[(size_t)s0 * 64 + L]);
        float2 x1 = __half22float2(H[(size_t)s1 * 64 + L]);
        float2 x2 = __half22float2(H[(size_t)s2 * 64 + L]);
        float2 x3 = __half22float2(H[(size_t)s3 * 64 + L]);
        a0.x += w0 * x0.x; a0.y += w0 * x0.y; d0 += w0;
        a1.x += w1 * x1.x; a1.y += w1 * x1.y; d1 += w1;
        a2.x += w2 * x2.x; a2.y += w2 * x2.y; d2 += w2;
        a3.x += w3 * x3.x; a3.y += w3 * x3.y; d3 += w3;
    }
    for (; j < e; ++j) {
        int s = csr_src[j];
        float w = wexp(as_h[s * 2] + ad);
        float2 xv = __half22float2(H[(size_t)s * 64 + L]);
        a0.x += w * xv.x; a0.y += w * xv.y; d0 += w;
    }

    float inv = 1.f / (((d0 + d1) + (d2 + d3)) + 1e-16f);
    float2 bb = ((const float2*)b1)[L];
    float vx = (a0.x + a1.x + a2.x + a3.x) * inv + bb.x;
    float vy = (a0.y + a1.y + a2.y + a3.y) * inv + bb.y;
    vx = vx > 0.f ? vx : expm1f(vx);
    vy = vy > 0.f ? vy : expm1f(vy);
    ((__half2*)(out1h + (size_t)node * 128))[L] = __floats2half2_rn(vx, vy);
}

// ---------------------------------------------------------------------------
// GEMM2 (MFMA fp16): h2[N,64pad fp16] = out1[N,128] @ W2[128,40].
// Wave = 16 nodes x 48 cols: 4 K-steps x 3 col-frags. Fused alpha2.
// ---------------------------------------------------------------------------
__global__ __launch_bounds__(256) void gemm2_k(
    const __half* __restrict__ out1h, const __half* __restrict__ W2h,
    const float* __restrict__ as2, const float* __restrict__ ad2,
    __half* __restrict__ h2h, float* __restrict__ asrc, float* __restrict__ adst)
{
    const int t = threadIdx.x;
    const int w = t >> 6, L = t & 63;
    const int lr = L & 15, lg = L >> 4;
    const int nbase = blockIdx.x * 64 + w * 16;

    float4v acc[3];
#pragma unroll
    for (int f = 0; f < 3; ++f) acc[f] = (float4v)0.f;

    int arow = nbase + lr; if (arow >= N_NODES) arow = N_NODES - 1;
    const __half* xrow = out1h + (size_t)arow * 128 + lg * 8;

#pragma unroll
    for (int ks = 0; ks < 4; ++ks) {
        half8v a = *(const half8v*)(xrow + ks * 32);
        const __half* wb = W2h + (size_t)ks * 1536 + (size_t)L * 8;
#pragma unroll
        for (int f = 0; f < 3; ++f) {
            half8v bfr = *(const half8v*)(wb + (size_t)f * 512);
            acc[f] = __builtin_amdgcn_mfma_f32_16x16x32_f16(a, bfr, acc[f], 0, 0, 0);
        }
    }

    float as_v[3], ad_v[3];
#pragma unroll
    for (int f = 0; f < 3; ++f) {
        int c = f * 16 + lr;
        as_v[f] = (c < 40) ? as2[c] : 0.f;
        ad_v[f] = (c < 40) ? ad2[c] : 0.f;
    }

#pragma unroll
    for (int r = 0; r < 4; ++r) {
        int node = nbase + lg * 4 + r;
        bool ok = node < N_NODES;
        if (ok) {
#pragma unroll
            for (int f = 0; f < 3; ++f)
                h2h[(size_t)node * 64 + f * 16 + lr] = __float2half_rn(acc[f][r]);
        }
        float ps = acc[0][r] * as_v[0] + acc[1][r] * as_v[1] + acc[2][r] * as_v[2];
        float pd = acc[0][r] * ad_v[0] + acc[1][r] * ad_v[1] + acc[2][r] * ad_v[2];
#pragma unroll
        for (int off = 1; off < 16; off <<= 1) {
            ps += __shfl_xor(ps, off);
            pd += __shfl_xor(pd, off);
        }
        if (lr == 0 && ok) {
            asrc[node] = ps;
            adst[node] = pd;
        }
    }
}

// ---------------------------------------------------------------------------
// Fused layer-2 aggregation + bias + log_softmax (R10 proven 4-wide form).
// ---------------------------------------------------------------------------
__global__ __launch_bounds__(256) void fagg2_k(
    const int* __restrict__ csr_src, const int* __restrict__ row_start,
    const float* __restrict__ asrc, const float* __restrict__ adst,
    const __half* __restrict__ h2h, const float* __restrict__ b2,
    float* __restrict__ out)
{
    int node = blockIdx.x * 4 + (threadIdx.x >> 6);
    int L = threadIdx.x & 63;
    bool act = L < 40;
    int col = act ? L : 0;
    int b = row_start[node], e = row_start[node + 1];
    float ad = adst[node];

    float a0 = 0.f, a1 = 0.f, a2 = 0.f, a3 = 0.f;
    float d0 = 0.f, d1 = 0.f, d2 = 0.f, d3 = 0.f;

    int j = b;
    for (; j + 3 < e; j += 4) {
        int s0 = csr_src[j], s1 = csr_src[j + 1], s2 = csr_src[j + 2], s3 = csr_src[j + 3];
        float w0 = wexp(asrc[s0] + ad);
        float w1 = wexp(asrc[s1] + ad);
        float w2 = wexp(asrc[s2] + ad);
        float w3 = wexp(asrc[s3] + ad);
        float x0 = __half2float(h2h[(size_t)s0 * 64 + col]);
        float x1 = __half2float(h2h[(size_t)s1 * 64 + col]);
        float x2 = __half2float(h2h[(size_t)s2 * 64 + col]);
        float x3 = __half2float(h2h[(size_t)s3 * 64 + col]);
        a0 += w0 * x0; d0 += w0;
        a1 += w1 * x1; d1 += w1;
        a2 += w2 * x2; d2 += w2;
        a3 += w3 * x3; d3 += w3;
    }
    for (; j < e; ++j) {
        int s = csr_src[j];
        float w = wexp(asrc[s] + ad);
        float xv = __half2float(h2h[(size_t)s * 64 + col]);
        a0 += w * xv; d0 += w;
    }

    float den = (d0 + d1) + (d2 + d3);
    float acc = (a0 + a1) + (a2 + a3);
    float v = act ? acc / (den + 1e-16f) + b2[L] : -1e30f;
    float mx = v;
#pragma unroll
    for (int off = 32; off; off >>= 1) mx = fmaxf(mx, __shfl_xor(mx, off));
    float ex = act ? __expf(v - mx) : 0.f;
#pragma unroll
    for (int off = 32; off; off >>= 1) ex += __shfl_xor(ex, off);
    if (act) out[(size_t)node * 40 + L] = v - mx - logf(ex);
}

// ---------------------------------------------------------------------------
extern "C" void kernel_launch(void* const* d_in, const int* in_sizes, int n_in,
                              void* d_out, int out_size, void* d_ws, size_t ws_size,
                              hipStream_t stream)
{
    const float* x   = (const float*)d_in[0];
    const int*   ei  = (const int*)d_in[1];
    const float* W1  = (const float*)d_in[2];
    const float* as1 = (const float*)d_in[3];
    const float* ad1 = (const float*)d_in[4];
    const float* b1  = (const float*)d_in[5];
    const float* W2  = (const float*)d_in[6];
    const float* as2 = (const float*)d_in[7];
    const float* ad2 = (const float*)d_in[8];
    const float* b2  = (const float*)d_in[9];
    float* out = (float*)d_out;

    float* ws = (float*)d_ws;
    // workspace layout (4B units); total ~27.4M = 109.6 MB
    __half* h1h   = (__half*)ws;                  // N*128 halves; reused as h2h (N*64 halves)
    __half* out1h = (__half*)(ws + 6400000);      // N*128 halves
    float* asrc1 = ws + 19200000;                 // 2N
    float* adst1 = ws + 19400000;                 // 2N
    float* asrc2 = ws + 19600000;                 // N
    float* adst2 = ws + 19700000;                 // N
    int* bcur      = (int*)(ws + 20110000);       // NB
    int* bbase     = (int*)(ws + 20111000);       // NB
    int* row_start = (int*)(ws + 20112000);       // N+1
    int* csr_src   = (int*)(ws + 20220000);       // E_TOT
    unsigned* bdata = (unsigned*)(ws + 22000000); // NB*BCAP = 2.1M
    unsigned short* xb  = (unsigned short*)(ws + 24100000);  // N*128 bf16
    unsigned short* W1b = (unsigned short*)(ws + 27300000);  // 16384 bf16
    __half* W2h = (__half*)(ws + 27310000);       // 6144 fp16

    // zero bucket cursors only (2 KB)
    hipMemsetAsync(bcur, 0, NB * sizeof(int), stream);

    // prep: x -> bf16, W1/W2 -> fragment order
    xprep_k<<<12500, 256, 0, stream>>>(x, xb);
    w1prep_k<<<1, 256, 0, stream>>>(W1, W1b);
    w2prep_k<<<1, 256, 0, stream>>>(W2, W2h);

    // CSR build: bin -> scan -> build
    bin_k<<<NBIN_WG, 256, 0, stream>>>(ei, bcur, bdata);
    scanb_k<<<1, 512, 0, stream>>>(bcur, bbase);
    build_k<<<NB, 256, 0, stream>>>(bdata, bcur, bbase, row_start, csr_src);

    // layer 1
    gemm1_k<<<1563, 256, 0, stream>>>(xb, W1b, as1, ad1, h1h, asrc1, adst1);
    fagg1_k<<<25000, 256, 0, stream>>>(csr_src, row_start, asrc1, adst1, h1h, b1, out1h);

    // layer 2 (h2h reuses h1h region, stride 64 halves = one 128B line)
    __half* h2h = h1h;
    gemm2_k<<<1563, 256, 0, stream>>>(out1h, W2h, as2, ad2, h2h, asrc2, adst2);
    fagg2_k<<<25000, 256, 0, stream>>>(csr_src, row_start, asrc2, adst2, h2h, b2, out);
}

// Round 15
// 252.556 us; speedup vs baseline: 1.3683x; 1.0660x over previous
//
#include <hip/hip_runtime.h>
#include <hip/hip_fp16.h>
#include <math.h>

#define N_NODES 100000
#define N_EDGES 1600000
#define E_TOT   (N_EDGES + N_NODES)

// bucketed CSR build
#define NB     512          // buckets
#define NPB    196          // dst-nodes per bucket (512*196 = 100352 >= N)
#define BCAP   4096         // capacity per bucket (mean 3332, +13 sigma)
#define BIN_CH 4096         // edges per bin_k workgroup
#define NBIN_WG ((E_TOT + BIN_CH - 1) / BIN_CH)

typedef __attribute__((ext_vector_type(8))) short short8v;      // 8 bf16
typedef __attribute__((ext_vector_type(8))) _Float16 half8v;    // 8 fp16
typedef __attribute__((ext_vector_type(4))) float float4v;

__device__ __forceinline__ float wexp(float v) {
    v = v > 0.f ? v : 0.2f * v;
    return __expf(v);
}

__device__ __forceinline__ unsigned short f2bf(float f) {
    unsigned u = __float_as_uint(f);
    return (unsigned short)((u + 0x7FFFu + ((u >> 16) & 1u)) >> 16);
}

// ---------------------------------------------------------------------------
// wprep: block 0 -> W1 bf16 fragment order [ks][f][lane][8] (16384 halves);
//        block 1 -> W2 fp16 fragment order [ks][f][lane][8], 3 col-frags
//        (48 cols, 40..47 zero; 6144 halves).
// ---------------------------------------------------------------------------
__global__ __launch_bounds__(256) void wprep_k(
    const float* __restrict__ W1, const float* __restrict__ W2,
    unsigned short* __restrict__ W1b, __half* __restrict__ W2h)
{
    if (blockIdx.x == 0) {
        for (int idx = threadIdx.x; idx < 16384; idx += 256) {
            int i    = idx & 7;
            int lane = (idx >> 3) & 63;
            int f    = (idx >> 9) & 7;
            int ks   = idx >> 12;
            int k   = ks * 32 + (lane >> 4) * 8 + i;
            int col = f * 16 + (lane & 15);
            W1b[idx] = f2bf(W1[k * 128 + col]);
        }
    } else {
        for (int idx = threadIdx.x; idx < 6144; idx += 256) {
            int i    = idx & 7;
            int lane = (idx >> 3) & 63;
            int rest = idx >> 9;          // 0..11
            int f = rest % 3, ks = rest / 3;
            int k   = ks * 32 + (lane >> 4) * 8 + i;
            int col = f * 16 + (lane & 15);
            W2h[idx] = __float2half_rn(col < 40 ? W2[k * 40 + col] : 0.f);
        }
    }
}

// ---------------------------------------------------------------------------
// GEMM1 (MFMA bf16, fused x-cast): h1[N,128] = x @ W1, fp16 out; fused alpha
// reductions. A-frag converted fp32->bf16 in-register (no xprep pass).
// Wave = 16 nodes x 128 cols: 4 K-steps x 8 col-frags of 16x16x32.
// C/D: col=lane&15, row=(lane>>4)*4+reg (m89-verified mapping).
// ---------------------------------------------------------------------------
__global__ __launch_bounds__(256) void gemm1_k(
    const float* __restrict__ x, const unsigned short* __restrict__ W1b,
    const float* __restrict__ as1, const float* __restrict__ ad1,
    __half* __restrict__ h1h, float* __restrict__ asrc, float* __restrict__ adst)
{
    const int t = threadIdx.x;
    const int w = t >> 6, L = t & 63;
    const int lr = L & 15;            // A-row / C-col within frag
    const int lg = L >> 4;            // k-group / C row-group
    const int nbase = blockIdx.x * 64 + w * 16;

    float4v acc[8];
#pragma unroll
    for (int f = 0; f < 8; ++f) acc[f] = (float4v)0.f;

    int arow = nbase + lr; if (arow >= N_NODES) arow = N_NODES - 1;
    const float* xrow = x + (size_t)arow * 128 + lg * 8;

#pragma unroll
    for (int ks = 0; ks < 4; ++ks) {
        float4 v0 = *(const float4*)(xrow + ks * 32);
        float4 v1 = *(const float4*)(xrow + ks * 32 + 4);
        short8v a;
        a[0] = (short)f2bf(v0.x); a[1] = (short)f2bf(v0.y);
        a[2] = (short)f2bf(v0.z); a[3] = (short)f2bf(v0.w);
        a[4] = (short)f2bf(v1.x); a[5] = (short)f2bf(v1.y);
        a[6] = (short)f2bf(v1.z); a[7] = (short)f2bf(v1.w);
        const unsigned short* wb = W1b + ((size_t)ks * 8 * 64 + L) * 8;
#pragma unroll
        for (int f = 0; f < 8; ++f) {
            short8v b = *(const short8v*)(wb + (size_t)f * 512);
            acc[f] = __builtin_amdgcn_mfma_f32_16x16x32_bf16(a, b, acc[f], 0, 0, 0);
        }
    }

    float as_v[8], ad_v[8];
#pragma unroll
    for (int f = 0; f < 8; ++f) {
        as_v[f] = as1[f * 16 + lr];
        ad_v[f] = ad1[f * 16 + lr];
    }

#pragma unroll
    for (int r = 0; r < 4; ++r) {
        int node = nbase + lg * 4 + r;
        bool ok = node < N_NODES;
        if (ok) {
#pragma unroll
            for (int f = 0; f < 8; ++f)
                h1h[(size_t)node * 128 + f * 16 + lr] = __float2half_rn(acc[f][r]);
        }
        float ps0 = 0.f, pd0 = 0.f, ps1 = 0.f, pd1 = 0.f;
#pragma unroll
        for (int f = 0; f < 4; ++f) { ps0 += acc[f][r] * as_v[f]; pd0 += acc[f][r] * ad_v[f]; }
#pragma unroll
        for (int f = 4; f < 8; ++f) { ps1 += acc[f][r] * as_v[f]; pd1 += acc[f][r] * ad_v[f]; }
#pragma unroll
        for (int off = 1; off < 16; off <<= 1) {
            ps0 += __shfl_xor(ps0, off); pd0 += __shfl_xor(pd0, off);
            ps1 += __shfl_xor(ps1, off); pd1 += __shfl_xor(pd1, off);
        }
        if (lr == 0 && ok) {
            asrc[node * 2 + 0] = ps0; asrc[node * 2 + 1] = ps1;
            adst[node * 2 + 0] = pd0; adst[node * 2 + 1] = pd1;
        }
    }
}

// ---------------------------------------------------------------------------
// CSR build, phase 1: bin edges by dst bucket. Edges read ONCE into regs.
// ---------------------------------------------------------------------------
__global__ __launch_bounds__(256) void bin_k(
    const int* __restrict__ ei, int* __restrict__ bcur, unsigned* __restrict__ bdata)
{
    __shared__ int hist[NB];
    __shared__ int base[NB];
    const int t = threadIdx.x;
    const int e0 = blockIdx.x * BIN_CH;

    int rs[16], rd[16];
#pragma unroll
    for (int p = 0; p < 16; ++p) {
        int e = e0 + p * 256 + t;
        if (e < E_TOT) {
            if (e < N_EDGES) { rs[p] = ei[e]; rd[p] = ei[N_EDGES + e]; }
            else             { rs[p] = rd[p] = e - N_EDGES; }
        } else rd[p] = -1;
    }

    for (int b = t; b < NB; b += 256) hist[b] = 0;
    __syncthreads();

#pragma unroll
    for (int p = 0; p < 16; ++p)
        if (rd[p] >= 0) atomicAdd(&hist[rd[p] / NPB], 1);
    __syncthreads();

    for (int b = t; b < NB; b += 256) {
        int c = hist[b];
        base[b] = c ? atomicAdd(&bcur[b], c) : 0;
        hist[b] = 0;      // reuse as local cursor
    }
    __syncthreads();

#pragma unroll
    for (int p = 0; p < 16; ++p) {
        if (rd[p] < 0) continue;
        int b  = rd[p] / NPB;
        int dl = rd[p] - b * NPB;
        int pos = base[b] + atomicAdd(&hist[b], 1);
        if (pos < BCAP)
            bdata[(size_t)b * BCAP + pos] = (unsigned)rs[p] | ((unsigned)dl << 17);
    }
}

// ---------------------------------------------------------------------------
// CSR build, phase 2a: exclusive scan of bucket counts (1 wg x 512 threads).
// ---------------------------------------------------------------------------
__global__ __launch_bounds__(512) void scanb_k(
    const int* __restrict__ bcur, int* __restrict__ bbase)
{
    __shared__ int a[NB], b_[NB];
    int t = threadIdx.x;
    int v = bcur[t];
    a[t] = v;
    __syncthreads();
    int* src = a; int* dst = b_;
    for (int off = 1; off < NB; off <<= 1) {
        dst[t] = (t >= off) ? src[t - off] + src[t] : src[t];
        __syncthreads();
        int* tmp = src; src = dst; dst = tmp;
    }
    bbase[t] = src[t] - v;   // exclusive
}

// ---------------------------------------------------------------------------
// CSR build, phase 2b: wg per bucket -> row_start + csr_src (contiguous).
// ---------------------------------------------------------------------------
__global__ __launch_bounds__(256) void build_k(
    const unsigned* __restrict__ bdata, const int* __restrict__ bcur,
    const int* __restrict__ bbase, int* __restrict__ row_start,
    int* __restrict__ csr_src)
{
    __shared__ unsigned rec[BCAP];     // 16 KB
    __shared__ int hist[256];
    __shared__ int excl[NPB];
    __shared__ int lcur[NPB];
    const int t = threadIdx.x;
    const int b = blockIdx.x;
    const int cnt = min(bcur[b], BCAP);
    const int bb = bbase[b];

    hist[t] = 0;
    if (t < NPB) lcur[t] = 0;
    __syncthreads();

    for (int i = t; i < cnt; i += 256) {
        unsigned r = bdata[(size_t)b * BCAP + i];
        rec[i] = r;
        atomicAdd(&hist[r >> 17], 1);
    }
    __syncthreads();

    int v = hist[t];
    __syncthreads();
    for (int off = 1; off < 256; off <<= 1) {
        int y = (t >= off) ? hist[t - off] : 0;
        __syncthreads();
        hist[t] += y;
        __syncthreads();
    }
    if (t < NPB) excl[t] = hist[t] - v;
    __syncthreads();

    int node = b * NPB + t;
    if (t < NPB && node <= N_NODES) row_start[node] = bb + excl[t];

    for (int i = t; i < cnt; i += 256) {
        unsigned r = rec[i];
        int dl = r >> 17;
        int s  = r & 0x1FFFF;
        int slot = atomicAdd(&lcur[dl], 1);
        csr_src[bb + excl[dl] + slot] = s;
    }
}

// ---------------------------------------------------------------------------
// Fused layer-1 aggregation (proven form: 4-wide, inline exp).
// ---------------------------------------------------------------------------
__global__ __launch_bounds__(256) void fagg1_k(
    const int* __restrict__ csr_src, const int* __restrict__ row_start,
    const float* __restrict__ asrc, const float* __restrict__ adst,
    const __half* __restrict__ h1h, const float* __restrict__ b1,
    __half* __restrict__ out1h)
{
    int node = blockIdx.x * 4 + (threadIdx.x >> 6);
    int L = threadIdx.x & 63;
    int h = L >> 5;
    int b = row_start[node], e = row_start[node + 1];
    const float* as_h = asrc + h;
    float ad = adst[node * 2 + h];
    const __half2* H = (const __half2*)h1h;

    float2 a0 = make_float2(0.f, 0.f), a1 = a0, a2 = a0, a3 = a0;
    float d0 = 0.f, d1 = 0.f, d2 = 0.f, d3 = 0.f;

    int j = b;
    for (; j + 3 < e; j += 4) {
        int s0 = csr_src[j], s1 = csr_src[j + 1], s2 = csr_src[j + 2], s3 = csr_src[j + 3];
        float w0 = wexp(as_h[s0 * 2] + ad);
        float w1 = wexp(as_h[s1 * 2] + ad);
        float w2 = wexp(as_h[s2 * 2] + ad);
        float w3 = wexp(as_h[s3 * 2] + ad);
        float2 x0 = __half22float2(H[(size_t)s0 * 64 + L]);
        float2 x1 = __half22float2(H[(size_t)s1 * 64 + L]);
        float2 x2 = __half22float2(H[(size_t)s2 * 64 + L]);
        float2 x3 = __half22float2(H[(size_t)s3 * 64 + L]);
        a0.x += w0 * x0.x; a0.y += w0 * x0.y; d0 += w0;
        a1.x += w1 * x1.x; a1.y += w1 * x1.y; d1 += w1;
        a2.x += w2 * x2.x; a2.y += w2 * x2.y; d2 += w2;
        a3.x += w3 * x3.x; a3.y += w3 * x3.y; d3 += w3;
    }
    for (; j < e; ++j) {
        int s = csr_src[j];
        float w = wexp(as_h[s * 2] + ad);
        float2 xv = __half22float2(H[(size_t)s * 64 + L]);
        a0.x += w * xv.x; a0.y += w * xv.y; d0 += w;
    }

    float inv = 1.f / (((d0 + d1) + (d2 + d3)) + 1e-16f);
    float2 bb = ((const float2*)b1)[L];
    float vx = (a0.x + a1.x + a2.x + a3.x) * inv + bb.x;
    float vy = (a0.y + a1.y + a2.y + a3.y) * inv + bb.y;
    vx = vx > 0.f ? vx : expm1f(vx);
    vy = vy > 0.f ? vy : expm1f(vy);
    ((__half2*)(out1h + (size_t)node * 128))[L] = __floats2half2_rn(vx, vy);
}

// ---------------------------------------------------------------------------
// GEMM2 (MFMA fp16): h2[N,64pad fp16] = out1[N,128] @ W2[128,40].
// Wave = 16 nodes x 48 cols: 4 K-steps x 3 col-frags. Fused alpha2.
// ---------------------------------------------------------------------------
__global__ __launch_bounds__(256) void gemm2_k(
    const __half* __restrict__ out1h, const __half* __restrict__ W2h,
    const float* __restrict__ as2, const float* __restrict__ ad2,
    __half* __restrict__ h2h, float* __restrict__ asrc, float* __restrict__ adst)
{
    const int t = threadIdx.x;
    const int w = t >> 6, L = t & 63;
    const int lr = L & 15, lg = L >> 4;
    const int nbase = blockIdx.x * 64 + w * 16;

    float4v acc[3];
#pragma unroll
    for (int f = 0; f < 3; ++f) acc[f] = (float4v)0.f;

    int arow = nbase + lr; if (arow >= N_NODES) arow = N_NODES - 1;
    const __half* xrow = out1h + (size_t)arow * 128 + lg * 8;

#pragma unroll
    for (int ks = 0; ks < 4; ++ks) {
        half8v a = *(const half8v*)(xrow + ks * 32);
        const __half* wb = W2h + (size_t)ks * 1536 + (size_t)L * 8;
#pragma unroll
        for (int f = 0; f < 3; ++f) {
            half8v bfr = *(const half8v*)(wb + (size_t)f * 512);
            acc[f] = __builtin_amdgcn_mfma_f32_16x16x32_f16(a, bfr, acc[f], 0, 0, 0);
        }
    }

    float as_v[3], ad_v[3];
#pragma unroll
    for (int f = 0; f < 3; ++f) {
        int c = f * 16 + lr;
        as_v[f] = (c < 40) ? as2[c] : 0.f;
        ad_v[f] = (c < 40) ? ad2[c] : 0.f;
    }

#pragma unroll
    for (int r = 0; r < 4; ++r) {
        int node = nbase + lg * 4 + r;
        bool ok = node < N_NODES;
        if (ok) {
#pragma unroll
            for (int f = 0; f < 3; ++f)
                h2h[(size_t)node * 64 + f * 16 + lr] = __float2half_rn(acc[f][r]);
        }
        float ps = acc[0][r] * as_v[0] + acc[1][r] * as_v[1] + acc[2][r] * as_v[2];
        float pd = acc[0][r] * ad_v[0] + acc[1][r] * ad_v[1] + acc[2][r] * ad_v[2];
#pragma unroll
        for (int off = 1; off < 16; off <<= 1) {
            ps += __shfl_xor(ps, off);
            pd += __shfl_xor(pd, off);
        }
        if (lr == 0 && ok) {
            asrc[node] = ps;
            adst[node] = pd;
        }
    }
}

// ---------------------------------------------------------------------------
// Fused layer-2 aggregation + bias + log_softmax (proven 4-wide form).
// ---------------------------------------------------------------------------
__global__ __launch_bounds__(256) void fagg2_k(
    const int* __restrict__ csr_src, const int* __restrict__ row_start,
    const float* __restrict__ asrc, const float* __restrict__ adst,
    const __half* __restrict__ h2h, const float* __restrict__ b2,
    float* __restrict__ out)
{
    int node = blockIdx.x * 4 + (threadIdx.x >> 6);
    int L = threadIdx.x & 63;
    bool act = L < 40;
    int col = act ? L : 0;
    int b = row_start[node], e = row_start[node + 1];
    float ad = adst[node];

    float a0 = 0.f, a1 = 0.f, a2 = 0.f, a3 = 0.f;
    float d0 = 0.f, d1 = 0.f, d2 = 0.f, d3 = 0.f;

    int j = b;
    for (; j + 3 < e; j += 4) {
        int s0 = csr_src[j], s1 = csr_src[j + 1], s2 = csr_src[j + 2], s3 = csr_src[j + 3];
        float w0 = wexp(asrc[s0] + ad);
        float w1 = wexp(asrc[s1] + ad);
        float w2 = wexp(asrc[s2] + ad);
        float w3 = wexp(asrc[s3] + ad);
        float x0 = __half2float(h2h[(size_t)s0 * 64 + col]);
        float x1 = __half2float(h2h[(size_t)s1 * 64 + col]);
        float x2 = __half2float(h2h[(size_t)s2 * 64 + col]);
        float x3 = __half2float(h2h[(size_t)s3 * 64 + col]);
        a0 += w0 * x0; d0 += w0;
        a1 += w1 * x1; d1 += w1;
        a2 += w2 * x2; d2 += w2;
        a3 += w3 * x3; d3 += w3;
    }
    for (; j < e; ++j) {
        int s = csr_src[j];
        float w = wexp(asrc[s] + ad);
        float xv = __half2float(h2h[(size_t)s * 64 + col]);
        a0 += w * xv; d0 += w;
    }

    float den = (d0 + d1) + (d2 + d3);
    float acc = (a0 + a1) + (a2 + a3);
    float v = act ? acc / (den + 1e-16f) + b2[L] : -1e30f;
    float mx = v;
#pragma unroll
    for (int off = 32; off; off >>= 1) mx = fmaxf(mx, __shfl_xor(mx, off));
    float ex = act ? __expf(v - mx) : 0.f;
#pragma unroll
    for (int off = 32; off; off >>= 1) ex += __shfl_xor(ex, off);
    if (act) out[(size_t)node * 40 + L] = v - mx - logf(ex);
}

// ---------------------------------------------------------------------------
extern "C" void kernel_launch(void* const* d_in, const int* in_sizes, int n_in,
                              void* d_out, int out_size, void* d_ws, size_t ws_size,
                              hipStream_t stream)
{
    const float* x   = (const float*)d_in[0];
    const int*   ei  = (const int*)d_in[1];
    const float* W1  = (const float*)d_in[2];
    const float* as1 = (const float*)d_in[3];
    const float* ad1 = (const float*)d_in[4];
    const float* b1  = (const float*)d_in[5];
    const float* W2  = (const float*)d_in[6];
    const float* as2 = (const float*)d_in[7];
    const float* ad2 = (const float*)d_in[8];
    const float* b2  = (const float*)d_in[9];
    float* out = (float*)d_out;

    float* ws = (float*)d_ws;
    // workspace layout (4B units); total ~24.2M = 96.8 MB
    __half* h1h   = (__half*)ws;                  // N*128 halves; reused as h2h (N*64 halves)
    __half* out1h = (__half*)(ws + 6400000);      // N*128 halves
    float* asrc1 = ws + 19200000;                 // 2N
    float* adst1 = ws + 19400000;                 // 2N
    float* asrc2 = ws + 19600000;                 // N
    float* adst2 = ws + 19700000;                 // N
    int* bcur      = (int*)(ws + 20110000);       // NB
    int* bbase     = (int*)(ws + 20111000);       // NB
    int* row_start = (int*)(ws + 20112000);       // N+1
    int* csr_src   = (int*)(ws + 20220000);       // E_TOT
    unsigned* bdata = (unsigned*)(ws + 22000000); // NB*BCAP = 2.1M
    unsigned short* W1b = (unsigned short*)(ws + 24100000);  // 16384 bf16
    __half* W2h = (__half*)(ws + 24110000);       // 6144 fp16

    // zero bucket cursors only (2 KB)
    hipMemsetAsync(bcur, 0, NB * sizeof(int), stream);

    // prep: W1/W2 -> fragment order (x cast fused into gemm1)
    wprep_k<<<2, 256, 0, stream>>>(W1, W2, W1b, W2h);

    // CSR build: bin -> scan -> build
    bin_k<<<NBIN_WG, 256, 0, stream>>>(ei, bcur, bdata);
    scanb_k<<<1, 512, 0, stream>>>(bcur, bbase);
    build_k<<<NB, 256, 0, stream>>>(bdata, bcur, bbase, row_start, csr_src);

    // layer 1
    gemm1_k<<<1563, 256, 0, stream>>>(x, W1b, as1, ad1, h1h, asrc1, adst1);
    fagg1_k<<<25000, 256, 0, stream>>>(csr_src, row_start, asrc1, adst1, h1h, b1, out1h);

    // layer 2 (h2h reuses h1h region, stride 64 halves = one 128B line)
    __half* h2h = h1h;
    gemm2_k<<<1563, 256, 0, stream>>>(out1h, W2h, as2, ad2, h2h, asrc2, adst2);
    fagg2_k<<<25000, 256, 0, stream>>>(csr_src, row_start, asrc2, adst2, h2h, b2, out);
}